// Round 9
// baseline (239.370 us; speedup 1.0000x reference)
//
#include <hip/hip_runtime.h>

#pragma clang fp contract(off)

#define HH 256
#define WW 256
#define NVERTS 6890
#define NFACES 13776
#define RASTN (NFACES + 1)          // +1 sentinel record (depth=BIG, never wins)
#define PAD1 14336                  // pass-1 plane length (= SLABS*SLABSZ), pad never passes
#define LISTSTRIDE 13824            // multiple of 128, >= NFACES
#define RCHUNK 32                   // faces per work item
#define MAXCH 432                   // LISTSTRIDE / RCHUNK
#define SLABS 4                     // bin blocks per tile
#define WSUB 896                    // faces per wave (14 x 64)
#define NITER 14
#define SLABSZ (4 * WSUB)           // 3584 faces per block; 4 slabs = 14336 >= NFACES
#define NBLK 2048                   // persistent raster blocks (x4 waves)
#define NWAVES (NBLK * 4)
#define BIGF 1000000000.0f
#define EPSF 1e-8f

// c(i) = ((i+0.5)/256)*2 - 1  -- exact in f32, matches reference pixel coords
__device__ __forceinline__ float pixc(int i) {
    return __fsub_rn(__fmul_rn(__fdiv_rn(__fadd_rn((float)i, 0.5f), 256.0f), 2.0f), 1.0f);
}

// order-preserving float->uint (all finite values, negatives included)
__device__ __forceinline__ unsigned int fsort(float f) {
    unsigned int u = __float_as_uint(f);
    return (u & 0x80000000u) ? ~u : (u | 0x80000000u);
}

// inverse of fsort; 0xFFFFFFFF (background sentinel) decodes to BIGF
__device__ __forceinline__ float funsort(unsigned int u) {
    if (u == 0xFFFFFFFFu) return BIGF;
    unsigned int v = (u & 0x80000000u) ? (u & 0x7FFFFFFFu) : ~u;
    return __uint_as_float(v);
}

// 64-B face record layout (floats):
// [0]=x2 [1]=y2 [2]=A [3]=B [4]=C [5]=D [6]=inv [7]=fid [8]=z0 [9]=z1 [10]=z2
// Degenerate / sentinel: A=B=C=D=0, inv=1 -> depth = exactly BIG, never wins.
// fz plane (separate, 4 B/face, index b*RASTN+f): conservative lower bound of
// the face's interpolated depth = min(z0,z1,z2) - 4e-6*sum|z| - 1e-30.
//
// ROUND-9 early-z: k-major + mask-up-front.  Round-8 post-mortem: the
// tile-max bound lb is BIGF while ANY tile pixel is uncovered; with
// tile-contiguous scheduling all of a tile's chunks ran concurrently on a
// ~32-deep zbuf -> lb=BIGF everywhere -> mask never culled (+7us overhead).
// Round-7 post-mortem: k-major ordering was right, but its per-face
// {load fzmin -> branch -> load record} serial chain killed pipelining
// (193us, VALU 9%).  This round combines the two correct halves:
//   - k-major direct iteration e = k*NT + tileG: all tiles' chunk k finish
//     ~one grid-stride window before chunk k+1; coverage doubles per window
//     (each chunk covers ~50% of tile pixels) so by window ~8 lb < BIG and
//     the remaining ~75% of entries cull.
//   - mask-up-front (round 8): per entry, one coalesced 32-face fz gather +
//     zbuf snapshot (agent-scope atomic loads; plain loads may serve stale
//     XCD-L2 lines -- stale is safe but defeats the cull) -> wave-max lb ->
//     one ballot -> 32-bit survivor mask in a register.  Per-face predicate
//     is a register bit; surviving record s_loads stay prefetchable.
// Cull validity: zbuf only decreases (atomicMin), so any snapshot >= final;
// culled face has d(p) >= fzmin > lb >= snapshot(p) >= final(p) at every
// pixel -> strictly loses every atomicMin -> skipping is bit-identical.
// zc stays BIGF-initialized, so exact-depth tie resolution (u64 atomicMin
// == lowest fid == reference's first-chunk/first-argmin) is untouched.
//
// NO per-block __threadfence() in bin (round-5: agent-scope fence =
// buffer_wbl2+buffer_inv walk of the 4 MiB XCD L2 per call; ordering is
// carried by device-scope atomic RMWs + the __syncthreads() vmcnt(0) drain).

// ---------------------------------------------------------------------------
// Kernel 1: precompute 64-B face records + fz plane + pass1 u8 tile ranges +
// SAT edge records + flow verts; zbuf init; control zero-init.
// ---------------------------------------------------------------------------
__global__ __launch_bounds__(256) void precompute_kernel(
    const float* __restrict__ src_cam, const float* __restrict__ src_verts,
    const float* __restrict__ tgt_cam, const float* __restrict__ tgt_verts,
    const int* __restrict__ faces,
    float4* __restrict__ rast64, float* __restrict__ fz,
    uchar4* __restrict__ pass1,
    float4* __restrict__ eplane,
    float4* __restrict__ flowg,
    unsigned long long* __restrict__ zbuf,
    int* __restrict__ counts, int* __restrict__ done, int* __restrict__ qcount,
    int B)
{
    int idx = blockIdx.x * blockDim.x + threadIdx.x;
    if (idx < B * HH * WW) zbuf[idx] = ~0ull;   // background sentinel
    if (counts && idx < B * 256) { counts[idx] = 0; done[idx] = 0; }
    if (qcount && idx == 0) qcount[0] = 0;
    if (idx >= B * PAD1) return;
    int b = idx / PAD1;
    int f = idx - b * PAD1;
    if (f >= NFACES) {
        // pad entries (incl. would-be sentinel slot): empty range, never pass
        if (pass1) pass1[(size_t)b * PAD1 + f] = make_uchar4(255, 255, 0, 0);
        if (f == NFACES) {   // sentinel raster record
            float4* rr = rast64 + ((size_t)b * RASTN + f) * 4;
            rr[0] = make_float4(0.0f, 0.0f, 0.0f, 0.0f);
            rr[1] = make_float4(0.0f, 0.0f, 1.0f, __int_as_float(-1));
            rr[2] = make_float4(BIGF, BIGF, BIGF, 0.0f);
            rr[3] = make_float4(0.0f, 0.0f, 0.0f, 0.0f);
            if (fz) fz[(size_t)b * RASTN + f] = BIGF;
        }
        return;
    }
    float4* rr = rast64 + ((size_t)b * RASTN + f) * 4;
    int i0 = faces[3*f+0], i1 = faces[3*f+1], i2 = faces[3*f+2];

    float tc0 = tgt_cam[3*b+0], tc1 = tgt_cam[3*b+1], tc2 = tgt_cam[3*b+2];
    const float* tv = tgt_verts + (size_t)b * NVERTS * 3;
    float x0 = __fmul_rn(tc0, __fadd_rn(tv[3*i0+0], tc1));
    float y0 = -__fmul_rn(tc0, __fadd_rn(tv[3*i0+1], tc2));
    float z0 = tv[3*i0+2];
    float x1 = __fmul_rn(tc0, __fadd_rn(tv[3*i1+0], tc1));
    float y1 = -__fmul_rn(tc0, __fadd_rn(tv[3*i1+1], tc2));
    float z1 = tv[3*i1+2];
    float x2 = __fmul_rn(tc0, __fadd_rn(tv[3*i2+0], tc1));
    float y2 = -__fmul_rn(tc0, __fadd_rn(tv[3*i2+1], tc2));
    float z2 = tv[3*i2+2];

    float A  = __fsub_rn(y1, y2);
    float D  = __fsub_rn(x0, x2);
    float Bc = __fsub_rn(x2, x1);
    float E_ = __fsub_rn(y0, y2);
    float denom = __fadd_rn(__fmul_rn(A, D), __fmul_rn(Bc, E_));
    bool valid = (fabsf(denom) >= EPSF);
    float inv = __fdiv_rn(1.0f, valid ? denom : 1.0f);
    float Cc = __fsub_rn(y2, y0);

    // conservative depth lower bound for early-z
    float fzmin = fminf(fminf(z0, z1), z2)
                - 4e-6f * (fabsf(z0) + fabsf(z1) + fabsf(z2)) - 1e-30f;

    if (valid) {
        rr[0] = make_float4(x2, y2, A, Bc);
        rr[1] = make_float4(Cc, D, inv, __int_as_float(f));
        rr[2] = make_float4(z0, z1, z2, 0.0f);
    } else {
        rr[0] = make_float4(0.0f, 0.0f, 0.0f, 0.0f);
        rr[1] = make_float4(0.0f, 0.0f, 1.0f, __int_as_float(f));
        rr[2] = make_float4(BIGF, BIGF, BIGF, 0.0f);
    }
    rr[3] = make_float4(0.0f, 0.0f, 0.0f, 0.0f);
    if (fz) fz[(size_t)b * RASTN + f] = valid ? fzmin : BIGF;

    uchar4 range;
    float4 e1, e2, e3;
    if (valid) {
        float xmn = fminf(fminf(x0, x1), x2), xmx = fmaxf(fmaxf(x0, x1), x2);
        float ymn = fminf(fminf(y0, y1), y2), ymx = fmaxf(fmaxf(y0, y1), y2);
        float S = fmaxf(fmaxf(fabsf(xmn), fabsf(xmx)),
                        fmaxf(fabsf(ymn), fabsf(ymx))) + 1.01f;
        float slop = 2e-6f * S;                       // ~32 eps * S
        float l0 = sqrtf(D*D + E_*E_);                // |v0-v2|
        float dx1v = x1 - x2, dy1v = y1 - y2;
        float l1 = sqrtf(dx1v*dx1v + dy1v*dy1v);      // |v1-v2|
        float dx2v = x1 - x0, dy2v = y1 - y0;
        float l2 = sqrtf(dx2v*dx2v + dy2v*dy2v);      // |v1-v0|
        float mp = fmaxf(fmaxf(l0*l1, l1*l2), l0*l2);
        float Ex = slop * mp / fabsf(denom);          // sliver extension
        float m = Ex + slop + 1e-4f;
        float bxmn = xmn - m, bymn = ymn - m, bxmx = xmx + m, bymx = ymx + m;

        // exact tile range: tile t overlaps iff bxmn<=pixc(16t+15) &&
        // bxmx>=pixc(16t).  Guess via float then fix up exactly.
        int txlo = (int)floorf((__fmul_rn(__fadd_rn(bxmn, 1.0f), 128.0f) - 15.5f) * 0.0625f);
        txlo = max(0, min(16, txlo));
        while (txlo > 0  && pixc(16*(txlo-1)+15) >= bxmn) txlo--;
        while (txlo < 16 && pixc(16*txlo+15)     <  bxmn) txlo++;
        int txhi = (int)floorf((__fmul_rn(__fadd_rn(bxmx, 1.0f), 128.0f) - 0.5f) * 0.0625f);
        txhi = max(-1, min(15, txhi));
        while (txhi < 15 && pixc(16*(txhi+1)) <= bxmx) txhi++;
        while (txhi >= 0 && pixc(16*txhi)     >  bxmx) txhi--;
        int tylo = (int)floorf((__fmul_rn(__fadd_rn(bymn, 1.0f), 128.0f) - 15.5f) * 0.0625f);
        tylo = max(0, min(16, tylo));
        while (tylo > 0  && pixc(16*(tylo-1)+15) >= bymn) tylo--;
        while (tylo < 16 && pixc(16*tylo+15)     <  bymn) tylo++;
        int tyhi = (int)floorf((__fmul_rn(__fadd_rn(bymx, 1.0f), 128.0f) - 0.5f) * 0.0625f);
        tyhi = max(-1, min(15, tyhi));
        while (tyhi < 15 && pixc(16*(tyhi+1)) <= bymx) tyhi++;
        while (tyhi >= 0 && pixc(16*tyhi)     >  bymx) tyhi--;
        if (txlo > txhi || tylo > tyhi || txlo > 15 || tylo > 15 ||
            txhi < 0 || tyhi < 0) {
            range = make_uchar4(255, 255, 0, 0);      // empty
        } else {
            range = make_uchar4((unsigned char)txlo, (unsigned char)tylo,
                                (unsigned char)txhi, (unsigned char)tyhi);
        }

        // SAT edge functions, sign-corrected so inside ⇔ F_i >= 0
        float s = (denom >= 0.0f) ? 1.0f : -1.0f;
        float gx0 = s * A,  gy0 = s * Bc;              // |grad| = l1
        float gx1 = s * Cc, gy1 = s * D;               // |grad| = l0
        float gx2 = s * (y0 - y1), gy2 = s * (x1 - x0); // |grad| = l2
        float b0 = -(gx0 * x2 + gy0 * y2);
        float b1 = -(gx1 * x2 + gy1 * y2);
        float b2 = fabsf(denom) - b0 - b1;
        float mm15 = 1.5f * m;
        float k0 = b0 + mm15 * l1 + 1e-6f;
        float k1 = b1 + mm15 * l0 + 1e-6f;
        float k2 = b2 + mm15 * l2 + 1e-6f;
        e1 = make_float4(gx0, gy0, k0, gx1);
        e2 = make_float4(gy1, k1, gx2, gy2);
        e3 = make_float4(k2, 0.0f, 0.0f, 0.0f);
    } else {
        range = make_uchar4(255, 255, 0, 0);          // empty -> never listed
        e1 = make_float4(0.0f, 0.0f, -1.0f, 0.0f);
        e2 = make_float4(0.0f, -1.0f, 0.0f, 0.0f);
        e3 = make_float4(-1.0f, 0.0f, 0.0f, 0.0f);
    }
    if (pass1) pass1[(size_t)b * PAD1 + f] = range;
    if (eplane) {
        float4* ep = eplane + ((size_t)b * NFACES + f) * 4;
        ep[0] = e1; ep[1] = e2; ep[2] = e3;
        ep[3] = make_float4(0.0f, 0.0f, 0.0f, 0.0f);
    }

    float sc0 = src_cam[3*b+0], sc1 = src_cam[3*b+1], sc2 = src_cam[3*b+2];
    const float* sv = src_verts + (size_t)b * NVERTS * 3;
    float g0x = __fmul_rn(sc0, __fadd_rn(sv[3*i0+0], sc1));
    float g0y = __fmul_rn(sc0, __fadd_rn(sv[3*i0+1], sc2));
    float g1x = __fmul_rn(sc0, __fadd_rn(sv[3*i1+0], sc1));
    float g1y = __fmul_rn(sc0, __fadd_rn(sv[3*i1+1], sc2));
    float g2x = __fmul_rn(sc0, __fadd_rn(sv[3*i2+0], sc1));
    float g2y = __fmul_rn(sc0, __fadd_rn(sv[3*i2+1], sc2));
    size_t fo = ((size_t)b * NFACES + f) * 2;
    flowg[fo+0] = make_float4(g0x, g0y, g1x, g1y);
    flowg[fo+1] = make_float4(g2x, g2y, 0.0f, 0.0f);
}

// ---------------------------------------------------------------------------
// Kernel 2: bin, two-phase, no device fence, no queue.  Finalizer pads the
// list to xRCHUNK, publishes done[tileG] = padded count (safe plain store:
// this block observed the last slab-counter increment, nobody else touches
// done[tileG]; kernel boundary publishes) and atomicMax(qcount, nchunks).
// ---------------------------------------------------------------------------
__global__ __launch_bounds__(256) void bin_kernel(
    const uchar4* __restrict__ pass1, const float4* __restrict__ eplane,
    int* __restrict__ lists,
    int* __restrict__ counts, int* __restrict__ done,
    int* __restrict__ qcount, int B)
{
    __shared__ int seg[4][WSUB];
    int tile = blockIdx.x;          // 0..255
    int slab = blockIdx.y;
    int b = blockIdx.z;
    int tileG = b * 256 + tile;
    int tX = tile & 15, tY = tile >> 4;
    float txmin = pixc(tX * 16), txmax = pixc(tX * 16 + 15);
    float tymin = pixc(tY * 16), tymax = pixc(tY * 16 + 15);

    int wv = threadIdx.x >> 6, lane = threadIdx.x & 63;
    const uchar4* p1 = pass1 + (size_t)b * PAD1;
    const float4* ep = eplane + (size_t)b * NFACES * 4;
    int* mylist = lists + (size_t)tileG * LISTSTRIDE;
    int wlo = slab * SLABSZ + wv * WSUB;
    int cnt = 0;

    int f0 = wlo + lane;
    uchar4 c = p1[f0];

    #pragma unroll
    for (int it = 0; it < NITER; ++it) {
        uchar4 n;
        if (it + 1 < NITER) n = p1[f0 + (it + 1) * 64];
        int f = f0 + it * 64;
        bool pass = (tX >= (int)c.x) & (tX <= (int)c.z) &
                    (tY >= (int)c.y) & (tY <= (int)c.w);
        unsigned long long m = __ballot(pass);
        if (pass) {
            int pre = __popcll(m & ((1ull << lane) - 1ull));
            seg[wv][cnt + pre] = f;
        }
        cnt += __popcll(m);
        c = n;
    }

    // pass 2: SAT refine, in-place compaction
    int outc = 0;
    for (int base = 0; base < cnt; base += 64) {
        int i = base + lane;
        int f = (i < cnt) ? seg[wv][i] : 0;
        const float4* er = ep + (size_t)f * 4;
        float4 e1 = er[0], e2 = er[1], e3 = er[2];
        float v0 = e1.x * (e1.x >= 0.0f ? txmax : txmin)
                 + e1.y * (e1.y >= 0.0f ? tymax : tymin) + e1.z;
        float v1 = e1.w * (e1.w >= 0.0f ? txmax : txmin)
                 + e2.x * (e2.x >= 0.0f ? tymax : tymin) + e2.y;
        float v2 = e2.z * (e2.z >= 0.0f ? txmax : txmin)
                 + e2.w * (e2.w >= 0.0f ? tymax : tymin) + e3.x;
        bool pass = (i < cnt) & (v0 >= 0.0f) & (v1 >= 0.0f) & (v2 >= 0.0f);
        unsigned long long m = __ballot(pass);
        if (pass) {
            int pre = __popcll(m & ((1ull << lane) - 1ull));
            seg[wv][outc + pre] = f;     // outc+pre <= i: safe in lockstep
        }
        outc += __popcll(m);
    }
    cnt = outc;

    int gbase = 0;
    if (lane == 0 && cnt) gbase = atomicAdd(&counts[tileG], cnt);
    gbase = __shfl(gbase, 0);
    for (int i = lane; i < cnt; i += 64) mylist[gbase + i] = seg[wv][i];

    __syncthreads();   // full vmcnt(0) drain: list stores + counts atomics done
    if (threadIdx.x < 64) {
        int isLast = 0, cc = 0;
        if (threadIdx.x == 0) {
            isLast = (atomicAdd(&done[tileG], 1) == SLABS - 1);
            if (isLast) cc = atomicAdd(&counts[tileG], 0);  // coherent read
        }
        isLast = __shfl(isLast, 0);
        if (isLast) {
            cc = __shfl(cc, 0);
            int padded = (cc + RCHUNK - 1) & ~(RCHUNK - 1);
            for (int i = cc + threadIdx.x; i < padded; i += 64)
                mylist[i] = NFACES;
            if (threadIdx.x == 0) {
                int nch = padded / RCHUNK;
                if (nch) atomicMax(qcount, nch);
                done[tileG] = padded;   // counter role finished; published
            }                           // at the kernel boundary
        }
    }
}

// ---------------------------------------------------------------------------
// Kernel 3: raster, k-major + mask-up-front early-z.  8192 persistent waves
// iterate e = k*NT + tileG (all tiles' chunk k before chunk k+1).  Per
// entry: coalesced 32-face list+fz gather, zbuf snapshot (agent-scope
// atomic loads), wave-max lb, one ballot -> register survivor mask;
// per-face predicate is a register bit, surviving 64-B record s_loads stay
// unconditional/prefetchable (round-7 lesson).  Per-pixel u64 atomicMin of
// (sortable_depth, fid) == exact lexicographic min == reference semantics;
// all depth math _rn -> bit-identical output.
// ---------------------------------------------------------------------------
__global__ __launch_bounds__(256) void raster_kernel(
    const float* __restrict__ rast64, const int* __restrict__ lists,
    const float* __restrict__ fz,
    const int* __restrict__ donep, const int* __restrict__ qcount,
    unsigned long long* __restrict__ zbuf, int B)
{
    int wv = threadIdx.x >> 6, lane = threadIdx.x & 63;
    int waveId = blockIdx.x * 4 + wv;
    int NT = B * 256;
    int qn;
    if (!lists) qn = B * 256 * MAXCH;            // unbinned fallback: dense
    else        qn = qcount[0] * NT;             // k-major index space
    qn = __builtin_amdgcn_readfirstlane(qn);

    for (int e = waveId; e < qn; e += NWAVES) {
        int tileG, k;
        if (!lists) {
            tileG = e / MAXCH; k = e - tileG * MAXCH;
        } else {
            k = e / NT; tileG = e - k * NT;
        }
        tileG = __builtin_amdgcn_readfirstlane(tileG);
        k = __builtin_amdgcn_readfirstlane(k);
        const int* lp = nullptr;
        if (lists) {
            if (k * RCHUNK >= donep[tileG]) continue;   // tile has fewer chunks
            lp = lists + (size_t)tileG * LISTSTRIDE + k * RCHUNK;
        }
        int b = tileG >> 8, tile = tileG & 255;
        const float* rb = rast64 + (size_t)b * RASTN * 16;

        int tX = tile & 15, tY = tile >> 4;
        int col = lane & 15, row0 = lane >> 4;
        int pxi = tX * 16 + col;
        float px = pixc(pxi);
        int ry0 = tY * 16 + row0;
        float py0 = pixc(ry0);
        float py1 = pixc(ry0 + 4);
        float py2 = pixc(ry0 + 8);
        float py3 = pixc(ry0 + 12);

        unsigned int mask = 0xFFFFFFFFu;
        if (lp) {
            // early-z survivor mask, computed entirely up front
            size_t zbase = ((size_t)b << 16) | (size_t)pxi;
            unsigned long long pk0 = __hip_atomic_load(
                &zbuf[zbase | ((size_t)ry0 << 8)],
                __ATOMIC_RELAXED, __HIP_MEMORY_SCOPE_AGENT);
            unsigned long long pk1 = __hip_atomic_load(
                &zbuf[zbase | ((size_t)(ry0 + 4) << 8)],
                __ATOMIC_RELAXED, __HIP_MEMORY_SCOPE_AGENT);
            unsigned long long pk2 = __hip_atomic_load(
                &zbuf[zbase | ((size_t)(ry0 + 8) << 8)],
                __ATOMIC_RELAXED, __HIP_MEMORY_SCOPE_AGENT);
            unsigned long long pk3 = __hip_atomic_load(
                &zbuf[zbase | ((size_t)(ry0 + 12) << 8)],
                __ATOMIC_RELAXED, __HIP_MEMORY_SCOPE_AGENT);
            float lb = fmaxf(fmaxf(funsort((unsigned int)(pk0 >> 32)),
                                   funsort((unsigned int)(pk1 >> 32))),
                             fmaxf(funsort((unsigned int)(pk2 >> 32)),
                                   funsort((unsigned int)(pk3 >> 32))));
            #pragma unroll
            for (int off = 1; off < 64; off <<= 1)
                lb = fmaxf(lb, __shfl_xor(lb, off, 64));
            // lane j<32 tests face j of this chunk
            int fidx = lp[lane & 31];
            float fzv = fz[(size_t)b * RASTN + fidx];
            unsigned long long bm = __ballot((lane < 32) & (fzv <= lb));
            mask = (unsigned int)bm;
            if (mask == 0u) continue;          // every face strictly loses
        }

        float z0c = BIGF, z1c = BIGF, z2c = BIGF, z3c = BIGF;
        int f0c = -1, f1c = -1, f2c = -1, f3c = -1;

        for (int j = 0; j < RCHUNK; j += 4) {
            unsigned int g = (mask >> j) & 0xFu;
            if (!g) continue;
            int4 fis;
            if (lp) {
                fis = *(const int4*)(lp + j);
            } else {
                int base = k * RCHUNK + j;
                fis.x = min(base + 0, NFACES); fis.y = min(base + 1, NFACES);
                fis.z = min(base + 2, NFACES); fis.w = min(base + 3, NFACES);
            }
            #pragma unroll
            for (int q = 0; q < 4; ++q) {
                if (!(g & (1u << q))) continue;
                int fi = (q == 0) ? fis.x : (q == 1) ? fis.y : (q == 2) ? fis.z : fis.w;
                fi = __builtin_amdgcn_readfirstlane(fi);
                const float* r = rb + (size_t)fi * 16;
                float X2 = r[0], Y2 = r[1], A = r[2], Bc = r[3];
                float Cc = r[4], Dd = r[5], inv = r[6];
                int   fid = __float_as_int(r[7]);
                float Z0 = r[8], Z1 = r[9], Z2 = r[10];

                float dx  = __fsub_rn(px, X2);
                float Adx = __fmul_rn(A, dx);
                float Cdx = __fmul_rn(Cc, dx);
                auto evalp = [&](float py, float& zc, int& fc) {
                    float dy = __fsub_rn(py, Y2);
                    float w0 = __fmul_rn(__fadd_rn(Adx, __fmul_rn(Bc, dy)), inv);
                    float w1 = __fmul_rn(__fadd_rn(Cdx, __fmul_rn(Dd, dy)), inv);
                    float w2 = __fsub_rn(__fsub_rn(1.0f, w0), w1);
                    float d  = __fadd_rn(__fadd_rn(__fmul_rn(w0, Z0), __fmul_rn(w1, Z1)),
                                         __fmul_rn(w2, Z2));
                    float mm = fminf(fminf(w0, w1), w2);    // v_min3
                    bool ins = (mm >= 0.0f) & (d < zc);
                    if (ins) { zc = d; fc = fid; }
                };
                evalp(py0, z0c, f0c);
                evalp(py1, z1c, f1c);
                evalp(py2, z2c, f2c);
                evalp(py3, z3c, f3c);
            }
        }

        auto commit = [&](int rowk, float zc, int fc) {
            if (fc >= 0) {
                unsigned long long pk =
                    ((unsigned long long)fsort(zc) << 32) | (unsigned int)fc;
                int pyi = ry0 + rowk * 4;
                atomicMin(&zbuf[((size_t)b << 16) | (pyi << 8) | pxi], pk);
            }
        };
        commit(0, z0c, f0c);
        commit(1, z1c, f1c);
        commit(2, z2c, f2c);
        commit(3, z3c, f3c);
    }
}

// ---------------------------------------------------------------------------
// Kernel 4: resolve. Per pixel: read winning fid, recompute w0,w1 from the
// record (same _rn sequence -> bit-identical), flow gather, bilinear sample.
// ---------------------------------------------------------------------------
__global__ __launch_bounds__(256) void resolve_kernel(
    const float* __restrict__ rast64, const float4* __restrict__ flowg,
    const unsigned long long* __restrict__ zbuf,
    const float* __restrict__ src_img, float* __restrict__ out, int B)
{
    int idx = blockIdx.x * 256 + threadIdx.x;
    if (idx >= B * HH * WW) return;
    int b = idx >> 16;
    int pix = idx & 65535;
    int pxi = pix & 255, pyi = pix >> 8;
    float px = pixc(pxi), py = pixc(pyi);

    unsigned int fid = (unsigned int)zbuf[idx];
    float fx, fy;
    if (fid != 0xFFFFFFFFu) {
        const float* r = rast64 + ((size_t)b * RASTN + fid) * 16;
        float dx = __fsub_rn(px, r[0]);
        float dy = __fsub_rn(py, r[1]);
        float w0 = __fmul_rn(__fadd_rn(__fmul_rn(r[2], dx), __fmul_rn(r[3], dy)), r[6]);
        float w1 = __fmul_rn(__fadd_rn(__fmul_rn(r[4], dx), __fmul_rn(r[5], dy)), r[6]);
        float w2 = __fsub_rn(__fsub_rn(1.0f, w0), w1);
        const float4* fg = flowg + ((size_t)b * NFACES + fid) * 2;
        float4 g0 = fg[0];
        float4 g1 = fg[1];
        fx = __fadd_rn(__fadd_rn(__fmul_rn(w0, g0.x), __fmul_rn(w1, g0.z)),
                       __fmul_rn(w2, g1.x));
        fy = __fadd_rn(__fadd_rn(__fmul_rn(w0, g0.y), __fmul_rn(w1, g0.w)),
                       __fmul_rn(w2, g1.y));
    } else {
        fx = -2.0f; fy = -2.0f;
    }

    float ix = __fmul_rn(__fsub_rn(__fmul_rn(__fadd_rn(fx, 1.0f), 256.0f), 1.0f), 0.5f);
    float iy = __fmul_rn(__fsub_rn(__fmul_rn(__fadd_rn(fy, 1.0f), 256.0f), 1.0f), 0.5f);
    ix = fminf(fmaxf(ix, 0.0f), 255.0f);
    iy = fminf(fmaxf(iy, 0.0f), 255.0f);
    float x0f = floorf(ix), y0f = floorf(iy);
    float wx = __fsub_rn(ix, x0f), wy = __fsub_rn(iy, y0f);
    int x0i = (int)x0f, y0i = (int)y0f;
    int x1i = min(x0i + 1, 255), y1i = min(y0i + 1, 255);
    float omwx = __fsub_rn(1.0f, wx), omwy = __fsub_rn(1.0f, wy);
    float wa = __fmul_rn(omwx, omwy);
    float wb = __fmul_rn(wx, omwy);
    float wc = __fmul_rn(omwx, wy);
    float wd = __fmul_rn(wx, wy);
    const float* img = src_img + (size_t)b * 3 * HH * WW;
    int o00 = y0i * WW + x0i, o01 = y0i * WW + x1i;
    int o10 = y1i * WW + x0i, o11 = y1i * WW + x1i;
    float* ob = out + (size_t)b * 3 * HH * WW + (size_t)pyi * WW + pxi;
    for (int c = 0; c < 3; ++c) {
        const float* ic = img + (size_t)c * HH * WW;
        float Ia = ic[o00], Ib = ic[o01], Ic = ic[o10], Id = ic[o11];
        float val = __fadd_rn(__fadd_rn(__fadd_rn(__fmul_rn(Ia, wa), __fmul_rn(Ib, wb)),
                                        __fmul_rn(Ic, wc)),
                              __fmul_rn(Id, wd));
        ob[(size_t)c * HH * WW] = val;
    }
}

extern "C" void kernel_launch(void* const* d_in, const int* in_sizes, int n_in,
                              void* d_out, int out_size, void* d_ws, size_t ws_size,
                              hipStream_t stream)
{
    const float* src_img   = (const float*)d_in[0];
    const float* src_cam   = (const float*)d_in[1];
    const float* src_verts = (const float*)d_in[2];
    const float* tgt_cam   = (const float*)d_in[3];
    const float* tgt_verts = (const float*)d_in[4];
    const int*   faces     = (const int*)d_in[5];
    int B = in_sizes[1] / 3;   // src_cam is [B,3]

    size_t off = 0;
    auto alloc = [&](size_t bytes) {
        size_t o = off;
        off = (off + bytes + 255) & ~(size_t)255;
        return o;
    };
    size_t rastOff = alloc((size_t)B * RASTN * 64);
    size_t fzOff   = alloc((size_t)B * RASTN * sizeof(float)); // fzmin plane
    size_t p1Off   = alloc((size_t)B * PAD1 * 4);          // u8 tile ranges
    size_t edgOff  = alloc((size_t)B * NFACES * 64);       // SAT edge records
    size_t flowOff = alloc((size_t)B * NFACES * 2 * sizeof(float4));
    size_t zbufOff = alloc((size_t)B * HH * WW * sizeof(unsigned long long));
    size_t cntOff  = alloc((size_t)B * 256 * sizeof(int));
    size_t donOff  = alloc((size_t)B * 256 * sizeof(int));
    size_t qcOff   = alloc(sizeof(int));
    size_t listOff = alloc((size_t)B * 256 * LISTSTRIDE * sizeof(int));
    bool binned = (off <= ws_size);

    char* ws = (char*)d_ws;
    float4* rast64 = (float4*)(ws + rastOff);
    float*  fz     = (float*)(ws + fzOff);
    uchar4* pass1  = binned ? (uchar4*)(ws + p1Off)  : nullptr;
    float4* eplane = binned ? (float4*)(ws + edgOff) : nullptr;
    float4* flowg  = (float4*)(ws + flowOff);
    unsigned long long* zbuf = (unsigned long long*)(ws + zbufOff);
    int* counts = binned ? (int*)(ws + cntOff) : nullptr;
    int* done   = binned ? (int*)(ws + donOff) : nullptr;
    int* qcount = binned ? (int*)(ws + qcOff)  : nullptr;
    int* lists  = binned ? (int*)(ws + listOff) : nullptr;

    int nInit = B * HH * WW;
    int nPre  = B * PAD1;
    int nMax  = nInit > nPre ? nInit : nPre;
    precompute_kernel<<<(nMax + 255) / 256, 256, 0, stream>>>(
        src_cam, src_verts, tgt_cam, tgt_verts, faces,
        rast64, fz, pass1, eplane, flowg, zbuf, counts, done, qcount, B);
    if (binned) {
        bin_kernel<<<dim3(256, SLABS, B), 256, 0, stream>>>(
            pass1, eplane, lists, counts, done, qcount, B);
        raster_kernel<<<NBLK, 256, 0, stream>>>(
            (const float*)rast64, lists, fz, done, qcount, zbuf, B);
    } else {
        raster_kernel<<<NBLK, 256, 0, stream>>>(
            (const float*)rast64, nullptr, fz, nullptr, nullptr, zbuf, B);
    }
    resolve_kernel<<<(B * HH * WW + 255) / 256, 256, 0, stream>>>(
        (const float*)rast64, flowg, zbuf, src_img, (float*)d_out, B);
}

// Round 10
// 139.579 us; speedup vs baseline: 1.7149x; 1.7149x over previous
//
#include <hip/hip_runtime.h>

#pragma clang fp contract(off)

#define HH 256
#define WW 256
#define NVERTS 6890
#define NFACES 13776
#define RASTN (NFACES + 1)          // +1 sentinel record (depth=BIG, never wins)
#define PAD1 14336                  // pass-1 plane length (= SLABS*SLABSZ), pad never passes
#define LISTSTRIDE 13824            // multiple of 128, >= NFACES
#define RCHUNK 32                   // faces per work item
#define MAXCH 432                   // LISTSTRIDE / RCHUNK
#define KSPLIT 16                   // chunks 0..15 -> pass A (no cull); 16+ -> pass B (cull)
#define SLABS 4                     // bin blocks per tile
#define WSUB 896                    // faces per wave (14 x 64)
#define NITER 14
#define SLABSZ (4 * WSUB)           // 3584 faces per block; 4 slabs = 14336 >= NFACES
#define NBLK 2048                   // persistent raster blocks (x4 waves)
#define NWAVES (NBLK * 4)
#define BIGF 1000000000.0f
#define EPSF 1e-8f

// c(i) = ((i+0.5)/256)*2 - 1  -- exact in f32, matches reference pixel coords
__device__ __forceinline__ float pixc(int i) {
    return __fsub_rn(__fmul_rn(__fdiv_rn(__fadd_rn((float)i, 0.5f), 256.0f), 2.0f), 1.0f);
}

// order-preserving float->uint (all finite values, negatives included)
__device__ __forceinline__ unsigned int fsort(float f) {
    unsigned int u = __float_as_uint(f);
    return (u & 0x80000000u) ? ~u : (u | 0x80000000u);
}

// inverse of fsort; 0xFFFFFFFF (background sentinel) decodes to BIGF
__device__ __forceinline__ float funsort(unsigned int u) {
    if (u == 0xFFFFFFFFu) return BIGF;
    unsigned int v = (u & 0x80000000u) ? (u & 0x7FFFFFFFu) : ~u;
    return __uint_as_float(v);
}

// 64-B face record layout (floats):
// [0]=x2 [1]=y2 [2]=A [3]=B [4]=C [5]=D [6]=inv [7]=fid [8]=z0 [9]=z1 [10]=z2
// Degenerate / sentinel: A=B=C=D=0, inv=1 -> depth = exactly BIG, never wins.
// fz plane (4 B/face, index b*RASTN+f): conservative lower bound of the
// face's interpolated depth = min(z0,z1,z2) - 4e-6*sum|z| - 1e-30.
//
// ROUND-10: revert to the round-6 structure (tile-contiguous queue, 46us
// raster) and split raster at a KERNEL BOUNDARY for the early-z cull.
// k-major is DEAD (r7: 193us, r9: 143us — same collapse with two different
// cull mechanisms; chunks k and k+16 of a tile map to the same wave ->
// heavy-tile serialization + idle-wave tail).  Instead:
//   pass A (no cull): chunks k<16 of every tile, exact round-6 hot loop.
//     After A, every tile has >=512 faces committed -> P(all 256 px
//     covered) ~ 99.6% -> the tile-max bound is non-vacuous.
//   pass B (cull): chunks k>=16 (heavy-tile tails).  r8's mask-up-front:
//     one coalesced 32-face fz gather + zbuf snapshot -> wave-max lb ->
//     one ballot -> register survivor mask; surviving record s_loads stay
//     unconditional/prefetchable.  Snapshots are PLAIN loads: the A->B
//     kernel boundary makes A's commits visible, and staleness within B
//     only loosens the bound (zbuf is monotone decreasing) -- safe.
// Cull validity: d(p) >= fzmin > lb >= snapshot >= final -> culled face
// strictly loses every u64 atomicMin -> skipping is bit-identical.  zc
// stays BIGF-initialized, tie semantics (lowest fid at equal depth ==
// reference first-argmin) untouched.
//
// NO per-block __threadfence() in bin (round-5: agent-scope fence =
// buffer_wbl2+buffer_inv walk of the 4 MiB XCD L2 per call; ordering is
// carried by device-scope atomic RMWs + the __syncthreads() vmcnt(0) drain).

// ---------------------------------------------------------------------------
// Kernel 1: precompute 64-B face records + fz plane + pass1 u8 tile ranges +
// SAT edge records + flow verts; zbuf init; control zero-init.
// ---------------------------------------------------------------------------
__global__ __launch_bounds__(256) void precompute_kernel(
    const float* __restrict__ src_cam, const float* __restrict__ src_verts,
    const float* __restrict__ tgt_cam, const float* __restrict__ tgt_verts,
    const int* __restrict__ faces,
    float4* __restrict__ rast64, float* __restrict__ fz,
    uchar4* __restrict__ pass1,
    float4* __restrict__ eplane,
    float4* __restrict__ flowg,
    unsigned long long* __restrict__ zbuf,
    int* __restrict__ counts, int* __restrict__ done,
    int* __restrict__ qcountA, int* __restrict__ qcountB,
    int B)
{
    int idx = blockIdx.x * blockDim.x + threadIdx.x;
    if (idx < B * HH * WW) zbuf[idx] = ~0ull;   // background sentinel
    if (counts && idx < B * 256) { counts[idx] = 0; done[idx] = 0; }
    if (qcountA && idx == 0) { qcountA[0] = 0; qcountB[0] = 0; }
    if (idx >= B * PAD1) return;
    int b = idx / PAD1;
    int f = idx - b * PAD1;
    if (f >= NFACES) {
        // pad entries (incl. would-be sentinel slot): empty range, never pass
        if (pass1) pass1[(size_t)b * PAD1 + f] = make_uchar4(255, 255, 0, 0);
        if (f == NFACES) {   // sentinel raster record
            float4* rr = rast64 + ((size_t)b * RASTN + f) * 4;
            rr[0] = make_float4(0.0f, 0.0f, 0.0f, 0.0f);
            rr[1] = make_float4(0.0f, 0.0f, 1.0f, __int_as_float(-1));
            rr[2] = make_float4(BIGF, BIGF, BIGF, 0.0f);
            rr[3] = make_float4(0.0f, 0.0f, 0.0f, 0.0f);
            if (fz) fz[(size_t)b * RASTN + f] = BIGF;
        }
        return;
    }
    float4* rr = rast64 + ((size_t)b * RASTN + f) * 4;
    int i0 = faces[3*f+0], i1 = faces[3*f+1], i2 = faces[3*f+2];

    float tc0 = tgt_cam[3*b+0], tc1 = tgt_cam[3*b+1], tc2 = tgt_cam[3*b+2];
    const float* tv = tgt_verts + (size_t)b * NVERTS * 3;
    float x0 = __fmul_rn(tc0, __fadd_rn(tv[3*i0+0], tc1));
    float y0 = -__fmul_rn(tc0, __fadd_rn(tv[3*i0+1], tc2));
    float z0 = tv[3*i0+2];
    float x1 = __fmul_rn(tc0, __fadd_rn(tv[3*i1+0], tc1));
    float y1 = -__fmul_rn(tc0, __fadd_rn(tv[3*i1+1], tc2));
    float z1 = tv[3*i1+2];
    float x2 = __fmul_rn(tc0, __fadd_rn(tv[3*i2+0], tc1));
    float y2 = -__fmul_rn(tc0, __fadd_rn(tv[3*i2+1], tc2));
    float z2 = tv[3*i2+2];

    float A  = __fsub_rn(y1, y2);
    float D  = __fsub_rn(x0, x2);
    float Bc = __fsub_rn(x2, x1);
    float E_ = __fsub_rn(y0, y2);
    float denom = __fadd_rn(__fmul_rn(A, D), __fmul_rn(Bc, E_));
    bool valid = (fabsf(denom) >= EPSF);
    float inv = __fdiv_rn(1.0f, valid ? denom : 1.0f);
    float Cc = __fsub_rn(y2, y0);

    // conservative depth lower bound for early-z
    float fzmin = fminf(fminf(z0, z1), z2)
                - 4e-6f * (fabsf(z0) + fabsf(z1) + fabsf(z2)) - 1e-30f;

    if (valid) {
        rr[0] = make_float4(x2, y2, A, Bc);
        rr[1] = make_float4(Cc, D, inv, __int_as_float(f));
        rr[2] = make_float4(z0, z1, z2, 0.0f);
    } else {
        rr[0] = make_float4(0.0f, 0.0f, 0.0f, 0.0f);
        rr[1] = make_float4(0.0f, 0.0f, 1.0f, __int_as_float(f));
        rr[2] = make_float4(BIGF, BIGF, BIGF, 0.0f);
    }
    rr[3] = make_float4(0.0f, 0.0f, 0.0f, 0.0f);
    if (fz) fz[(size_t)b * RASTN + f] = valid ? fzmin : BIGF;

    uchar4 range;
    float4 e1, e2, e3;
    if (valid) {
        float xmn = fminf(fminf(x0, x1), x2), xmx = fmaxf(fmaxf(x0, x1), x2);
        float ymn = fminf(fminf(y0, y1), y2), ymx = fmaxf(fmaxf(y0, y1), y2);
        float S = fmaxf(fmaxf(fabsf(xmn), fabsf(xmx)),
                        fmaxf(fabsf(ymn), fabsf(ymx))) + 1.01f;
        float slop = 2e-6f * S;                       // ~32 eps * S
        float l0 = sqrtf(D*D + E_*E_);                // |v0-v2|
        float dx1v = x1 - x2, dy1v = y1 - y2;
        float l1 = sqrtf(dx1v*dx1v + dy1v*dy1v);      // |v1-v2|
        float dx2v = x1 - x0, dy2v = y1 - y0;
        float l2 = sqrtf(dx2v*dx2v + dy2v*dy2v);      // |v1-v0|
        float mp = fmaxf(fmaxf(l0*l1, l1*l2), l0*l2);
        float Ex = slop * mp / fabsf(denom);          // sliver extension
        float m = Ex + slop + 1e-4f;
        float bxmn = xmn - m, bymn = ymn - m, bxmx = xmx + m, bymx = ymx + m;

        // exact tile range: tile t overlaps iff bxmn<=pixc(16t+15) &&
        // bxmx>=pixc(16t).  Guess via float then fix up exactly.
        int txlo = (int)floorf((__fmul_rn(__fadd_rn(bxmn, 1.0f), 128.0f) - 15.5f) * 0.0625f);
        txlo = max(0, min(16, txlo));
        while (txlo > 0  && pixc(16*(txlo-1)+15) >= bxmn) txlo--;
        while (txlo < 16 && pixc(16*txlo+15)     <  bxmn) txlo++;
        int txhi = (int)floorf((__fmul_rn(__fadd_rn(bxmx, 1.0f), 128.0f) - 0.5f) * 0.0625f);
        txhi = max(-1, min(15, txhi));
        while (txhi < 15 && pixc(16*(txhi+1)) <= bxmx) txhi++;
        while (txhi >= 0 && pixc(16*txhi)     >  bxmx) txhi--;
        int tylo = (int)floorf((__fmul_rn(__fadd_rn(bymn, 1.0f), 128.0f) - 15.5f) * 0.0625f);
        tylo = max(0, min(16, tylo));
        while (tylo > 0  && pixc(16*(tylo-1)+15) >= bymn) tylo--;
        while (tylo < 16 && pixc(16*tylo+15)     <  bymn) tylo++;
        int tyhi = (int)floorf((__fmul_rn(__fadd_rn(bymx, 1.0f), 128.0f) - 0.5f) * 0.0625f);
        tyhi = max(-1, min(15, tyhi));
        while (tyhi < 15 && pixc(16*(tyhi+1)) <= bymx) tyhi++;
        while (tyhi >= 0 && pixc(16*tyhi)     >  bymx) tyhi--;
        if (txlo > txhi || tylo > tyhi || txlo > 15 || tylo > 15 ||
            txhi < 0 || tyhi < 0) {
            range = make_uchar4(255, 255, 0, 0);      // empty
        } else {
            range = make_uchar4((unsigned char)txlo, (unsigned char)tylo,
                                (unsigned char)txhi, (unsigned char)tyhi);
        }

        // SAT edge functions, sign-corrected so inside ⇔ F_i >= 0
        float s = (denom >= 0.0f) ? 1.0f : -1.0f;
        float gx0 = s * A,  gy0 = s * Bc;              // |grad| = l1
        float gx1 = s * Cc, gy1 = s * D;               // |grad| = l0
        float gx2 = s * (y0 - y1), gy2 = s * (x1 - x0); // |grad| = l2
        float b0 = -(gx0 * x2 + gy0 * y2);
        float b1 = -(gx1 * x2 + gy1 * y2);
        float b2 = fabsf(denom) - b0 - b1;
        float mm15 = 1.5f * m;
        float k0 = b0 + mm15 * l1 + 1e-6f;
        float k1 = b1 + mm15 * l0 + 1e-6f;
        float k2 = b2 + mm15 * l2 + 1e-6f;
        e1 = make_float4(gx0, gy0, k0, gx1);
        e2 = make_float4(gy1, k1, gx2, gy2);
        e3 = make_float4(k2, 0.0f, 0.0f, 0.0f);
    } else {
        range = make_uchar4(255, 255, 0, 0);          // empty -> never listed
        e1 = make_float4(0.0f, 0.0f, -1.0f, 0.0f);
        e2 = make_float4(0.0f, -1.0f, 0.0f, 0.0f);
        e3 = make_float4(-1.0f, 0.0f, 0.0f, 0.0f);
    }
    if (pass1) pass1[(size_t)b * PAD1 + f] = range;
    if (eplane) {
        float4* ep = eplane + ((size_t)b * NFACES + f) * 4;
        ep[0] = e1; ep[1] = e2; ep[2] = e3;
        ep[3] = make_float4(0.0f, 0.0f, 0.0f, 0.0f);
    }

    float sc0 = src_cam[3*b+0], sc1 = src_cam[3*b+1], sc2 = src_cam[3*b+2];
    const float* sv = src_verts + (size_t)b * NVERTS * 3;
    float g0x = __fmul_rn(sc0, __fadd_rn(sv[3*i0+0], sc1));
    float g0y = __fmul_rn(sc0, __fadd_rn(sv[3*i0+1], sc2));
    float g1x = __fmul_rn(sc0, __fadd_rn(sv[3*i1+0], sc1));
    float g1y = __fmul_rn(sc0, __fadd_rn(sv[3*i1+1], sc2));
    float g2x = __fmul_rn(sc0, __fadd_rn(sv[3*i2+0], sc1));
    float g2y = __fmul_rn(sc0, __fadd_rn(sv[3*i2+1], sc2));
    size_t fo = ((size_t)b * NFACES + f) * 2;
    flowg[fo+0] = make_float4(g0x, g0y, g1x, g1y);
    flowg[fo+1] = make_float4(g2x, g2y, 0.0f, 0.0f);
}

// ---------------------------------------------------------------------------
// Kernel 2: bin (round-6 structure), two queues: A = chunks k<KSPLIT,
// B = chunks k>=KSPLIT.  LAST finishing slab pads to xRCHUNK + enqueues.
// ---------------------------------------------------------------------------
__global__ __launch_bounds__(256) void bin_kernel(
    const uchar4* __restrict__ pass1, const float4* __restrict__ eplane,
    int* __restrict__ lists,
    int* __restrict__ counts, int* __restrict__ done,
    unsigned int* __restrict__ queueA, int* __restrict__ qcountA,
    unsigned int* __restrict__ queueB, int* __restrict__ qcountB, int B)
{
    __shared__ int seg[4][WSUB];
    int tile = blockIdx.x;          // 0..255
    int slab = blockIdx.y;
    int b = blockIdx.z;
    int tileG = b * 256 + tile;
    int tX = tile & 15, tY = tile >> 4;
    float txmin = pixc(tX * 16), txmax = pixc(tX * 16 + 15);
    float tymin = pixc(tY * 16), tymax = pixc(tY * 16 + 15);

    int wv = threadIdx.x >> 6, lane = threadIdx.x & 63;
    const uchar4* p1 = pass1 + (size_t)b * PAD1;
    const float4* ep = eplane + (size_t)b * NFACES * 4;
    int* mylist = lists + (size_t)tileG * LISTSTRIDE;
    int wlo = slab * SLABSZ + wv * WSUB;
    int cnt = 0;

    int f0 = wlo + lane;
    uchar4 c = p1[f0];

    #pragma unroll
    for (int it = 0; it < NITER; ++it) {
        uchar4 n;
        if (it + 1 < NITER) n = p1[f0 + (it + 1) * 64];
        int f = f0 + it * 64;
        bool pass = (tX >= (int)c.x) & (tX <= (int)c.z) &
                    (tY >= (int)c.y) & (tY <= (int)c.w);
        unsigned long long m = __ballot(pass);
        if (pass) {
            int pre = __popcll(m & ((1ull << lane) - 1ull));
            seg[wv][cnt + pre] = f;
        }
        cnt += __popcll(m);
        c = n;
    }

    // pass 2: SAT refine, in-place compaction
    int outc = 0;
    for (int base = 0; base < cnt; base += 64) {
        int i = base + lane;
        int f = (i < cnt) ? seg[wv][i] : 0;
        const float4* er = ep + (size_t)f * 4;
        float4 e1 = er[0], e2 = er[1], e3 = er[2];
        float v0 = e1.x * (e1.x >= 0.0f ? txmax : txmin)
                 + e1.y * (e1.y >= 0.0f ? tymax : tymin) + e1.z;
        float v1 = e1.w * (e1.w >= 0.0f ? txmax : txmin)
                 + e2.x * (e2.x >= 0.0f ? tymax : tymin) + e2.y;
        float v2 = e2.z * (e2.z >= 0.0f ? txmax : txmin)
                 + e2.w * (e2.w >= 0.0f ? tymax : tymin) + e3.x;
        bool pass = (i < cnt) & (v0 >= 0.0f) & (v1 >= 0.0f) & (v2 >= 0.0f);
        unsigned long long m = __ballot(pass);
        if (pass) {
            int pre = __popcll(m & ((1ull << lane) - 1ull));
            seg[wv][outc + pre] = f;     // outc+pre <= i: safe in lockstep
        }
        outc += __popcll(m);
    }
    cnt = outc;

    int gbase = 0;
    if (lane == 0 && cnt) gbase = atomicAdd(&counts[tileG], cnt);
    gbase = __shfl(gbase, 0);
    for (int i = lane; i < cnt; i += 64) mylist[gbase + i] = seg[wv][i];

    __syncthreads();   // full vmcnt(0) drain: list stores + counts atomics done
    if (threadIdx.x < 64) {
        int isLast = 0, cc = 0;
        if (threadIdx.x == 0) {
            isLast = (atomicAdd(&done[tileG], 1) == SLABS - 1);
            if (isLast) cc = atomicAdd(&counts[tileG], 0);  // coherent read
        }
        isLast = __shfl(isLast, 0);
        if (isLast) {
            cc = __shfl(cc, 0);
            int padded = (cc + RCHUNK - 1) & ~(RCHUNK - 1);
            for (int i = cc + threadIdx.x; i < padded; i += 64)
                mylist[i] = NFACES;
            int nch = padded / RCHUNK;
            int na = min(nch, KSPLIT);
            int nb = nch - na;
            if (na) {
                int qb = 0;
                if (threadIdx.x == 0) qb = atomicAdd(qcountA, na);
                qb = __shfl(qb, 0);
                for (int kk = threadIdx.x; kk < na; kk += 64)
                    queueA[qb + kk] =
                        ((unsigned int)tileG << 10) | (unsigned int)kk;
            }
            if (nb) {
                int qb = 0;
                if (threadIdx.x == 0) qb = atomicAdd(qcountB, nb);
                qb = __shfl(qb, 0);
                for (int kk = threadIdx.x; kk < nb; kk += 64)
                    queueB[qb + kk] =
                        ((unsigned int)tileG << 10) | (unsigned int)(KSPLIT + kk);
            }
        }
    }
}

// ---------------------------------------------------------------------------
// Kernel 3: raster (round-6 structure).  cull=0 (pass A): exact round-6 hot
// loop, no mask.  cull=1 (pass B): mask-up-front early-z -- coalesced
// 32-face fz gather + PLAIN zbuf snapshot (A->B kernel boundary publishes
// A's commits; staleness within B only loosens the bound: zbuf is monotone
// decreasing), wave-max lb, one ballot -> register survivor mask; surviving
// 64-B record s_loads stay unconditional/prefetchable.
// Per-pixel u64 atomicMin of (sortable_depth, fid) == exact lexicographic
// min == reference semantics; all depth math _rn -> bit-identical output.
// ---------------------------------------------------------------------------
__global__ __launch_bounds__(256) void raster_kernel(
    const float* __restrict__ rast64, const int* __restrict__ lists,
    const float* __restrict__ fz,
    const unsigned int* __restrict__ queue, const int* __restrict__ qcount,
    unsigned long long* __restrict__ zbuf, int B, int cull)
{
    int wv = threadIdx.x >> 6, lane = threadIdx.x & 63;
    int waveId = blockIdx.x * 4 + wv;
    int qn = queue ? qcount[0] : B * 256 * MAXCH;
    qn = __builtin_amdgcn_readfirstlane(qn);

    for (int e = waveId; e < qn; e += NWAVES) {
        int tileG, k;
        if (queue) {
            unsigned int ent = queue[e];
            tileG = (int)(ent >> 10); k = (int)(ent & 1023u);
        } else {
            tileG = e / MAXCH; k = e - tileG * MAXCH;
        }
        tileG = __builtin_amdgcn_readfirstlane(tileG);
        k = __builtin_amdgcn_readfirstlane(k);
        const int* lp = lists ? (lists + (size_t)tileG * LISTSTRIDE + k * RCHUNK)
                              : nullptr;
        int b = tileG >> 8, tile = tileG & 255;
        const float* rb = rast64 + (size_t)b * RASTN * 16;

        int tX = tile & 15, tY = tile >> 4;
        int col = lane & 15, row0 = lane >> 4;
        int pxi = tX * 16 + col;
        float px = pixc(pxi);
        int ry0 = tY * 16 + row0;
        float py0 = pixc(ry0);
        float py1 = pixc(ry0 + 4);
        float py2 = pixc(ry0 + 8);
        float py3 = pixc(ry0 + 12);

        float z0c = BIGF, z1c = BIGF, z2c = BIGF, z3c = BIGF;
        int f0c = -1, f1c = -1, f2c = -1, f3c = -1;

        if (cull && lp) {
            // --- pass B: mask-up-front early-z ---
            size_t zbase = ((size_t)b << 16) | (size_t)pxi;
            unsigned long long pk0 = zbuf[zbase | ((size_t)ry0 << 8)];
            unsigned long long pk1 = zbuf[zbase | ((size_t)(ry0 + 4) << 8)];
            unsigned long long pk2 = zbuf[zbase | ((size_t)(ry0 + 8) << 8)];
            unsigned long long pk3 = zbuf[zbase | ((size_t)(ry0 + 12) << 8)];
            float lb = fmaxf(fmaxf(funsort((unsigned int)(pk0 >> 32)),
                                   funsort((unsigned int)(pk1 >> 32))),
                             fmaxf(funsort((unsigned int)(pk2 >> 32)),
                                   funsort((unsigned int)(pk3 >> 32))));
            #pragma unroll
            for (int off = 1; off < 64; off <<= 1)
                lb = fmaxf(lb, __shfl_xor(lb, off, 64));
            int fidx = lp[lane & 31];
            float fzv = fz[(size_t)b * RASTN + fidx];
            unsigned long long bm = __ballot((lane < 32) & (fzv <= lb));
            unsigned int mask = (unsigned int)bm;
            if (mask == 0u) continue;          // every face strictly loses

            for (int j = 0; j < RCHUNK; j += 4) {
                unsigned int g = (mask >> j) & 0xFu;
                if (!g) continue;
                int4 fis = *(const int4*)(lp + j);
                #pragma unroll
                for (int q = 0; q < 4; ++q) {
                    if (!(g & (1u << q))) continue;
                    int fi = (q == 0) ? fis.x : (q == 1) ? fis.y
                           : (q == 2) ? fis.z : fis.w;
                    fi = __builtin_amdgcn_readfirstlane(fi);
                    const float* r = rb + (size_t)fi * 16;
                    float X2 = r[0], Y2 = r[1], A = r[2], Bc = r[3];
                    float Cc = r[4], Dd = r[5], inv = r[6];
                    int   fid = __float_as_int(r[7]);
                    float Z0 = r[8], Z1 = r[9], Z2 = r[10];
                    float dx  = __fsub_rn(px, X2);
                    float Adx = __fmul_rn(A, dx);
                    float Cdx = __fmul_rn(Cc, dx);
                    auto evalp = [&](float py, float& zc, int& fc) {
                        float dy = __fsub_rn(py, Y2);
                        float w0 = __fmul_rn(__fadd_rn(Adx, __fmul_rn(Bc, dy)), inv);
                        float w1 = __fmul_rn(__fadd_rn(Cdx, __fmul_rn(Dd, dy)), inv);
                        float w2 = __fsub_rn(__fsub_rn(1.0f, w0), w1);
                        float d  = __fadd_rn(__fadd_rn(__fmul_rn(w0, Z0),
                                                       __fmul_rn(w1, Z1)),
                                             __fmul_rn(w2, Z2));
                        float mm = fminf(fminf(w0, w1), w2);
                        bool ins = (mm >= 0.0f) & (d < zc);
                        if (ins) { zc = d; fc = fid; }
                    };
                    evalp(py0, z0c, f0c);
                    evalp(py1, z1c, f1c);
                    evalp(py2, z2c, f2c);
                    evalp(py3, z3c, f3c);
                }
            }
        } else {
            // --- pass A / fallback: exact round-6 hot loop ---
            for (int j = 0; j < RCHUNK; j += 4) {
                int4 fis;
                if (lp) {
                    fis = *(const int4*)(lp + j);
                } else {
                    int base = k * RCHUNK + j;
                    fis.x = min(base + 0, NFACES); fis.y = min(base + 1, NFACES);
                    fis.z = min(base + 2, NFACES); fis.w = min(base + 3, NFACES);
                }
                #pragma unroll
                for (int q = 0; q < 4; ++q) {
                    int fi = (q == 0) ? fis.x : (q == 1) ? fis.y
                           : (q == 2) ? fis.z : fis.w;
                    fi = __builtin_amdgcn_readfirstlane(fi);
                    const float* r = rb + (size_t)fi * 16;
                    float X2 = r[0], Y2 = r[1], A = r[2], Bc = r[3];
                    float Cc = r[4], Dd = r[5], inv = r[6];
                    int   fid = __float_as_int(r[7]);
                    float Z0 = r[8], Z1 = r[9], Z2 = r[10];
                    float dx  = __fsub_rn(px, X2);
                    float Adx = __fmul_rn(A, dx);
                    float Cdx = __fmul_rn(Cc, dx);
                    auto evalp = [&](float py, float& zc, int& fc) {
                        float dy = __fsub_rn(py, Y2);
                        float w0 = __fmul_rn(__fadd_rn(Adx, __fmul_rn(Bc, dy)), inv);
                        float w1 = __fmul_rn(__fadd_rn(Cdx, __fmul_rn(Dd, dy)), inv);
                        float w2 = __fsub_rn(__fsub_rn(1.0f, w0), w1);
                        float d  = __fadd_rn(__fadd_rn(__fmul_rn(w0, Z0),
                                                       __fmul_rn(w1, Z1)),
                                             __fmul_rn(w2, Z2));
                        float mm = fminf(fminf(w0, w1), w2);
                        bool ins = (mm >= 0.0f) & (d < zc);
                        if (ins) { zc = d; fc = fid; }
                    };
                    evalp(py0, z0c, f0c);
                    evalp(py1, z1c, f1c);
                    evalp(py2, z2c, f2c);
                    evalp(py3, z3c, f3c);
                }
            }
        }

        auto commit = [&](int rowk, float zc, int fc) {
            if (fc >= 0) {
                unsigned long long pk =
                    ((unsigned long long)fsort(zc) << 32) | (unsigned int)fc;
                int pyi = ry0 + rowk * 4;
                atomicMin(&zbuf[((size_t)b << 16) | (pyi << 8) | pxi], pk);
            }
        };
        commit(0, z0c, f0c);
        commit(1, z1c, f1c);
        commit(2, z2c, f2c);
        commit(3, z3c, f3c);
    }
}

// ---------------------------------------------------------------------------
// Kernel 4: resolve. Per pixel: read winning fid, recompute w0,w1 from the
// record (same _rn sequence -> bit-identical), flow gather, bilinear sample.
// ---------------------------------------------------------------------------
__global__ __launch_bounds__(256) void resolve_kernel(
    const float* __restrict__ rast64, const float4* __restrict__ flowg,
    const unsigned long long* __restrict__ zbuf,
    const float* __restrict__ src_img, float* __restrict__ out, int B)
{
    int idx = blockIdx.x * 256 + threadIdx.x;
    if (idx >= B * HH * WW) return;
    int b = idx >> 16;
    int pix = idx & 65535;
    int pxi = pix & 255, pyi = pix >> 8;
    float px = pixc(pxi), py = pixc(pyi);

    unsigned int fid = (unsigned int)zbuf[idx];
    float fx, fy;
    if (fid != 0xFFFFFFFFu) {
        const float* r = rast64 + ((size_t)b * RASTN + fid) * 16;
        float dx = __fsub_rn(px, r[0]);
        float dy = __fsub_rn(py, r[1]);
        float w0 = __fmul_rn(__fadd_rn(__fmul_rn(r[2], dx), __fmul_rn(r[3], dy)), r[6]);
        float w1 = __fmul_rn(__fadd_rn(__fmul_rn(r[4], dx), __fmul_rn(r[5], dy)), r[6]);
        float w2 = __fsub_rn(__fsub_rn(1.0f, w0), w1);
        const float4* fg = flowg + ((size_t)b * NFACES + fid) * 2;
        float4 g0 = fg[0];
        float4 g1 = fg[1];
        fx = __fadd_rn(__fadd_rn(__fmul_rn(w0, g0.x), __fmul_rn(w1, g0.z)),
                       __fmul_rn(w2, g1.x));
        fy = __fadd_rn(__fadd_rn(__fmul_rn(w0, g0.y), __fmul_rn(w1, g0.w)),
                       __fmul_rn(w2, g1.y));
    } else {
        fx = -2.0f; fy = -2.0f;
    }

    float ix = __fmul_rn(__fsub_rn(__fmul_rn(__fadd_rn(fx, 1.0f), 256.0f), 1.0f), 0.5f);
    float iy = __fmul_rn(__fsub_rn(__fmul_rn(__fadd_rn(fy, 1.0f), 256.0f), 1.0f), 0.5f);
    ix = fminf(fmaxf(ix, 0.0f), 255.0f);
    iy = fminf(fmaxf(iy, 0.0f), 255.0f);
    float x0f = floorf(ix), y0f = floorf(iy);
    float wx = __fsub_rn(ix, x0f), wy = __fsub_rn(iy, y0f);
    int x0i = (int)x0f, y0i = (int)y0f;
    int x1i = min(x0i + 1, 255), y1i = min(y0i + 1, 255);
    float omwx = __fsub_rn(1.0f, wx), omwy = __fsub_rn(1.0f, wy);
    float wa = __fmul_rn(omwx, omwy);
    float wb = __fmul_rn(wx, omwy);
    float wc = __fmul_rn(omwx, wy);
    float wd = __fmul_rn(wx, wy);
    const float* img = src_img + (size_t)b * 3 * HH * WW;
    int o00 = y0i * WW + x0i, o01 = y0i * WW + x1i;
    int o10 = y1i * WW + x0i, o11 = y1i * WW + x1i;
    float* ob = out + (size_t)b * 3 * HH * WW + (size_t)pyi * WW + pxi;
    for (int c = 0; c < 3; ++c) {
        const float* ic = img + (size_t)c * HH * WW;
        float Ia = ic[o00], Ib = ic[o01], Ic = ic[o10], Id = ic[o11];
        float val = __fadd_rn(__fadd_rn(__fadd_rn(__fmul_rn(Ia, wa), __fmul_rn(Ib, wb)),
                                        __fmul_rn(Ic, wc)),
                              __fmul_rn(Id, wd));
        ob[(size_t)c * HH * WW] = val;
    }
}

extern "C" void kernel_launch(void* const* d_in, const int* in_sizes, int n_in,
                              void* d_out, int out_size, void* d_ws, size_t ws_size,
                              hipStream_t stream)
{
    const float* src_img   = (const float*)d_in[0];
    const float* src_cam   = (const float*)d_in[1];
    const float* src_verts = (const float*)d_in[2];
    const float* tgt_cam   = (const float*)d_in[3];
    const float* tgt_verts = (const float*)d_in[4];
    const int*   faces     = (const int*)d_in[5];
    int B = in_sizes[1] / 3;   // src_cam is [B,3]

    size_t off = 0;
    auto alloc = [&](size_t bytes) {
        size_t o = off;
        off = (off + bytes + 255) & ~(size_t)255;
        return o;
    };
    size_t rastOff = alloc((size_t)B * RASTN * 64);
    size_t fzOff   = alloc((size_t)B * RASTN * sizeof(float)); // fzmin plane
    size_t p1Off   = alloc((size_t)B * PAD1 * 4);          // u8 tile ranges
    size_t edgOff  = alloc((size_t)B * NFACES * 64);       // SAT edge records
    size_t flowOff = alloc((size_t)B * NFACES * 2 * sizeof(float4));
    size_t zbufOff = alloc((size_t)B * HH * WW * sizeof(unsigned long long));
    size_t cntOff  = alloc((size_t)B * 256 * sizeof(int));
    size_t donOff  = alloc((size_t)B * 256 * sizeof(int));
    size_t qcAOff  = alloc(sizeof(int));
    size_t qcBOff  = alloc(sizeof(int));
    size_t quAOff  = alloc((size_t)B * 256 * KSPLIT * sizeof(unsigned int));
    size_t quBOff  = alloc((size_t)B * 256 * MAXCH * sizeof(unsigned int));
    size_t listOff = alloc((size_t)B * 256 * LISTSTRIDE * sizeof(int));
    bool binned = (off <= ws_size);

    char* ws = (char*)d_ws;
    float4* rast64 = (float4*)(ws + rastOff);
    float*  fz     = (float*)(ws + fzOff);
    uchar4* pass1  = binned ? (uchar4*)(ws + p1Off)  : nullptr;
    float4* eplane = binned ? (float4*)(ws + edgOff) : nullptr;
    float4* flowg  = (float4*)(ws + flowOff);
    unsigned long long* zbuf = (unsigned long long*)(ws + zbufOff);
    int* counts = binned ? (int*)(ws + cntOff) : nullptr;
    int* done   = binned ? (int*)(ws + donOff) : nullptr;
    int* qcountA = binned ? (int*)(ws + qcAOff) : nullptr;
    int* qcountB = binned ? (int*)(ws + qcBOff) : nullptr;
    unsigned int* queueA = binned ? (unsigned int*)(ws + quAOff) : nullptr;
    unsigned int* queueB = binned ? (unsigned int*)(ws + quBOff) : nullptr;
    int* lists  = binned ? (int*)(ws + listOff) : nullptr;

    int nInit = B * HH * WW;
    int nPre  = B * PAD1;
    int nMax  = nInit > nPre ? nInit : nPre;
    precompute_kernel<<<(nMax + 255) / 256, 256, 0, stream>>>(
        src_cam, src_verts, tgt_cam, tgt_verts, faces,
        rast64, fz, pass1, eplane, flowg, zbuf, counts, done,
        qcountA, qcountB, B);
    if (binned) {
        bin_kernel<<<dim3(256, SLABS, B), 256, 0, stream>>>(
            pass1, eplane, lists, counts, done,
            queueA, qcountA, queueB, qcountB, B);
        // pass A: chunks k<16, no cull (exact round-6 hot loop)
        raster_kernel<<<NBLK, 256, 0, stream>>>(
            (const float*)rast64, lists, fz, queueA, qcountA, zbuf, B, 0);
        // pass B: chunks k>=16, mask-up-front early-z vs the >=512-deep zbuf
        raster_kernel<<<NBLK, 256, 0, stream>>>(
            (const float*)rast64, lists, fz, queueB, qcountB, zbuf, B, 1);
    } else {
        raster_kernel<<<NBLK, 256, 0, stream>>>(
            (const float*)rast64, nullptr, fz, nullptr, nullptr, zbuf, B, 0);
    }
    resolve_kernel<<<(B * HH * WW + 255) / 256, 256, 0, stream>>>(
        (const float*)rast64, flowg, zbuf, src_img, (float*)d_out, B);
}